// Round 17
// baseline (666.473 us; speedup 1.0000x reference)
//
#include <hip/hip_runtime.h>

#define T_STEPS 1000
#define BATCH   256
#define NHID    200
#define ROWF    200      // floats per LDS row (800 B, 16B-aligned)
#define BETA_C  0.85f
#define THR_C   1.0f

// WT2 row i (source neuron i) holds at float offset lo*4+k (lo<50,k<4):
// Wrec[(lo+50k)][i]. Lane lo reads ONE ds_read_b128 per firing source i,
// yielding weights for outputs {lo, lo+50, lo+100, lo+150}.
//
// 4 waves per batch element; wave w gathers source word w (~7 firing) and
// owns output word w. Parity-transposed exchange -> ONE lgkm-only barrier
// per step (round 15). NEW vs round 15:
//  (a) x-prefetch issued right AFTER the barrier, so its SMEM latency is
//      drained by the NEXT step's barrier (~800+ cyc away), not this one's.
//  (b) gather trips issue up to 8 loads (4 + branchy 4) before one counted
//      wait chain — no sentinel dummies, no extra bank conflicts, and the
//      adds are the identical ops in identical ascending order (bit-exact).
// cur2 recomputed by a second kernel from stored spikes.

#define BARRIER_LGKM \
    asm volatile("s_waitcnt lgkmcnt(0)\n\ts_barrier" ::: "memory");

__launch_bounds__(256, 1)
__global__ void rsnn_kernel(const float* __restrict__ X,
                            const float* __restrict__ W1,
                            const float* __restrict__ b1,
                            const float* __restrict__ Wrec,
                            const float* __restrict__ brec,
                            float* __restrict__ out_spk) {
#pragma clang fp contract(off)
    __shared__ float WT2[NHID * ROWF];   // 160,000 B
    __shared__ float part[4][4][50];     //   3,200 B

    const int tid = threadIdx.x;
    const int l   = tid & 63;            // lane
    const int w   = tid >> 6;            // wave id = source & output word id
    const int b   = blockIdx.x;

    // ---- stage Wrec (permuted transpose) into LDS ----
    for (int idx = tid; idx < NHID * NHID; idx += 256) {
        int r  = idx / NHID;             // Wrec row  (output neuron)
        int i  = idx - r * NHID;         // Wrec col  (source neuron)
        int lo = r % 50, k = r / 50;
        WT2[i * ROWF + lo * 4 + k] = Wrec[idx];
    }
    __syncthreads();

    const int lc = (l < 50) ? l : 49;    // lanes 50-63 duplicate lane 49
    const int oc = 50 * w + lc;          // this lane's output neuron
    const float w10 = W1[oc * 3 + 0], w11 = W1[oc * 3 + 1], w12 = W1[oc * 3 + 2];
    const float b1j = b1[oc], brj = brec[oc];

    float mem = 0.f;
    unsigned long long bm = 0;           // own word's spike mask

    const float* xp = X + (size_t)b * 3;
    float x0 = xp[0], x1 = xp[1], x2 = xp[2];

    const float* ldsrow  = WT2 + (size_t)lc * 4;
    const int    wbase   = 50 * w;
    float*       spk_out = out_spk + (size_t)b * NHID + wbase + lc;

// Gather trip: extract+issue 4, then (wave-uniform branch) 4 more if bits
// remain, then accumulate both groups. Same adds, same ascending order as
// the plain 4-wide loop -> bit-exact; one wait chain per up-to-8 loads.
#define REC_WORD(MASK, BASE)                                                          \
    {                                                                                 \
        unsigned long long m = (MASK);                                                \
        while (m) {                                                                   \
            int i0 = __builtin_ctzll(m); m &= m - 1;                                  \
            bool h1 = m != 0; int i1 = h1 ? __builtin_ctzll(m) : i0; if (h1) m &= m - 1; \
            bool h2 = m != 0; int i2 = h2 ? __builtin_ctzll(m) : i0; if (h2) m &= m - 1; \
            bool h3 = m != 0; int i3 = h3 ? __builtin_ctzll(m) : i0; if (h3) m &= m - 1; \
            const float4 v0 = *(const float4*)(ldsrow + (i0 + (BASE)) * ROWF);        \
            const float4 v1 = *(const float4*)(ldsrow + (i1 + (BASE)) * ROWF);        \
            const float4 v2 = *(const float4*)(ldsrow + (i2 + (BASE)) * ROWF);        \
            const float4 v3 = *(const float4*)(ldsrow + (i3 + (BASE)) * ROWF);        \
            bool s8 = m != 0;                                                         \
            int  i4 = i0, i5 = i0, i6 = i0, i7 = i0;                                  \
            bool h5 = false, h6 = false, h7 = false;                                  \
            float4 v4 = v0, v5 = v0, v6 = v0, v7 = v0;                                \
            if (s8) {                                                                 \
                i4 = __builtin_ctzll(m); m &= m - 1;                                  \
                h5 = m != 0; i5 = h5 ? __builtin_ctzll(m) : i4; if (h5) m &= m - 1;   \
                h6 = m != 0; i6 = h6 ? __builtin_ctzll(m) : i4; if (h6) m &= m - 1;   \
                h7 = m != 0; i7 = h7 ? __builtin_ctzll(m) : i4; if (h7) m &= m - 1;   \
                v4 = *(const float4*)(ldsrow + (i4 + (BASE)) * ROWF);                 \
                v5 = *(const float4*)(ldsrow + (i5 + (BASE)) * ROWF);                 \
                v6 = *(const float4*)(ldsrow + (i6 + (BASE)) * ROWF);                 \
                v7 = *(const float4*)(ldsrow + (i7 + (BASE)) * ROWF);                 \
            }                                                                         \
            pr0 += v0.x; pr1 += v0.y; pr2 += v0.z; pr3 += v0.w;                       \
            if (h1) { pr0 += v1.x; pr1 += v1.y; pr2 += v1.z; pr3 += v1.w; }           \
            if (h2) { pr0 += v2.x; pr1 += v2.y; pr2 += v2.z; pr3 += v2.w; }           \
            if (h3) { pr0 += v3.x; pr1 += v3.y; pr2 += v3.z; pr3 += v3.w; }           \
            if (s8) {                                                                 \
                pr0 += v4.x; pr1 += v4.y; pr2 += v4.z; pr3 += v4.w;                   \
                if (h5) { pr0 += v5.x; pr1 += v5.y; pr2 += v5.z; pr3 += v5.w; }       \
                if (h6) { pr0 += v6.x; pr1 += v6.y; pr2 += v6.z; pr3 += v6.w; }       \
                if (h7) { pr0 += v7.x; pr1 += v7.y; pr2 += v7.z; pr3 += v7.w; }       \
            }                                                                         \
        }                                                                             \
    }

// One time step. WRITES/READS select the parity-transposed layout.
// x-prefetch sits AFTER the barrier: its lgkm latency is drained only by the
// NEXT step's barrier, a full read+update+gather (~800 cyc) later.
#define STEP(T, WR0, WR1, WR2, WR3, RD0, RD1, RD2, RD3)                  \
    {                                                                    \
        const int t = (T);                                               \
                                                                         \
        float pr0 = 0.f, pr1 = 0.f, pr2 = 0.f, pr3 = 0.f;                \
        REC_WORD(bm, wbase)                                              \
                                                                         \
        if (l < 50) { WR0 = pr0; WR1 = pr1; WR2 = pr2; WR3 = pr3; }      \
        BARRIER_LGKM                                                     \
                                                                         \
        int   tn  = (t + 1 < T_STEPS) ? t + 1 : t;                       \
        float nx0 = xp[(size_t)tn * BATCH * 3 + 0];                      \
        float nx1 = xp[(size_t)tn * BATCH * 3 + 1];                      \
        float nx2 = xp[(size_t)tn * BATCH * 3 + 2];                      \
                                                                         \
        float p0 = RD0, p1 = RD1, p2 = RD2, p3 = RD3;                    \
        float rec = ((p0 + p1) + p2) + p3;                               \
                                                                         \
        float c1 = fmaf(x2, w12, fmaf(x1, w11, x0 * w10)) + b1j;         \
        float ba = ((BETA_C * mem + c1) + rec) + brj;                    \
        float nm = (mem > THR_C) ? 0.f : ba;                             \
        float sp = (nm > THR_C) ? 1.f : 0.f;                             \
        mem = nm;                                                        \
                                                                         \
        if (l < 50)                                                      \
            spk_out[(size_t)t * BATCH * NHID] = sp;                      \
        bm = __ballot((l < 50) && (sp > 0.5f));                          \
                                                                         \
        x0 = nx0; x1 = nx1; x2 = nx2;                                    \
    }

    for (int tt = 0; tt < T_STEPS; tt += 2) {
        // even step: write part[c][w], read part[w][s]
        STEP(tt,
             part[0][w][l], part[1][w][l], part[2][w][l], part[3][w][l],
             part[w][0][lc], part[w][1][lc], part[w][2][lc], part[w][3][lc])
        // odd step: write part[w][c], read part[s][w]
        STEP(tt + 1,
             part[w][0][l], part[w][1][l], part[w][2][l], part[w][3][l],
             part[0][w][lc], part[1][w][lc], part[2][w][lc], part[3][w][lc])
    }
#undef STEP
#undef REC_WORD
}

// cur2[t,b] = sum_j spk[t,b,j]*W2[j] + b2 — recomputed from stored spikes
// (L3-resident). Terminal output: tree reduction order is safe.
__launch_bounds__(256)
__global__ void cur2_kernel(const float* __restrict__ spk,
                            const float* __restrict__ W2,
                            const float* __restrict__ b2,
                            float* __restrict__ out) {
    const int lane = threadIdx.x & 63;
    const int wid  = (int)((blockIdx.x * blockDim.x + threadIdx.x) >> 6);
    const int nw   = (int)((gridDim.x * blockDim.x) >> 6);

    float4 w2v = {0.f, 0.f, 0.f, 0.f};
    if (lane < 50) w2v = *(const float4*)(W2 + lane * 4);
    const float b2v = b2[0];

    for (int p = wid; p < T_STEPS * BATCH; p += nw) {
        float4 sv = {0.f, 0.f, 0.f, 0.f};
        if (lane < 50) sv = *(const float4*)(spk + (size_t)p * NHID + lane * 4);
        float a = fmaf(sv.w, w2v.w, fmaf(sv.z, w2v.z,
                  fmaf(sv.y, w2v.y, sv.x * w2v.x)));
#pragma unroll
        for (int o = 32; o >= 1; o >>= 1) a += __shfl_xor(a, o);
        if (lane == 0) out[p] = a + b2v;   // p = t*BATCH + b
    }
}

extern "C" void kernel_launch(void* const* d_in, const int* in_sizes, int n_in,
                              void* d_out, int out_size, void* d_ws, size_t ws_size,
                              hipStream_t stream) {
    const float* X    = (const float*)d_in[0];
    const float* W1   = (const float*)d_in[1];
    const float* b1   = (const float*)d_in[2];
    const float* Wrec = (const float*)d_in[3];
    const float* brec = (const float*)d_in[4];
    const float* W2   = (const float*)d_in[5];
    const float* b2   = (const float*)d_in[6];

    float* out_cur2 = (float*)d_out;                            // [T,B,1] flat
    float* out_spk  = (float*)d_out + (size_t)T_STEPS * BATCH;  // [T,B,200] flat

    rsnn_kernel<<<BATCH, 256, 0, stream>>>(X, W1, b1, Wrec, brec, out_spk);
    cur2_kernel<<<1024, 256, 0, stream>>>(out_spk, W2, b2, out_cur2);
}

// Round 19
// 507.265 us; speedup vs baseline: 1.3139x; 1.3139x over previous
//
#include <hip/hip_runtime.h>

#define T_STEPS 1000
#define BATCH   256
#define NHID    200
#define ROWF    200      // floats per LDS row (800 B, 16B-aligned)
#define BETA_C  0.85f
#define THR_C   1.0f

// WT2 row i (source neuron i) holds at float offset lo*4+k (lo<50,k<4):
// Wrec[(lo+50k)][i]. Lane lo reads ONE ds_read_b128 per firing source i,
// yielding weights for outputs {lo, lo+50, lo+100, lo+150}.
//
// 4 waves per batch element; wave w gathers source word w (~7 firing) and
// owns output word w. TWO-barrier fixed-layout exchange (round 13, 4x
// validated under graph replay): write part[c][w] -> BAR -> read part[w][s]
// + reduce -> BAR -> update. Every cross-step write/read pair is separated
// by a full barrier — no parity reasoning, no same-wave-ordering reliance
// (round 18's single-barrier variant flaked re-validation at tighter pacing).
// Inputs batched 8 steps at a time into registers: per-step lgkmcnt(0)
// drains then cover DS only (SMEM shares lgkmcnt; the ~200-cyc L2 scalar
// latency is paid once per 8 steps instead of every step).
// cur2 recomputed by a second kernel from stored spikes.

#define BARRIER_LGKM \
    asm volatile("s_waitcnt lgkmcnt(0)\n\ts_barrier" ::: "memory");

__launch_bounds__(256, 1)
__global__ void rsnn_kernel(const float* __restrict__ X,
                            const float* __restrict__ W1,
                            const float* __restrict__ b1,
                            const float* __restrict__ Wrec,
                            const float* __restrict__ brec,
                            float* __restrict__ out_spk) {
#pragma clang fp contract(off)
    __shared__ float WT2[NHID * ROWF];   // 160,000 B
    __shared__ float part[4][4][50];     //   3,200 B  [comp][src wave][lane]

    const int tid = threadIdx.x;
    const int l   = tid & 63;            // lane
    const int w   = tid >> 6;            // wave id = source & output word id
    const int b   = blockIdx.x;

    // ---- stage Wrec (permuted transpose) into LDS ----
    for (int idx = tid; idx < NHID * NHID; idx += 256) {
        int r  = idx / NHID;             // Wrec row  (output neuron)
        int i  = idx - r * NHID;         // Wrec col  (source neuron)
        int lo = r % 50, k = r / 50;
        WT2[i * ROWF + lo * 4 + k] = Wrec[idx];
    }
    __syncthreads();

    const int lc = (l < 50) ? l : 49;    // lanes 50-63 duplicate lane 49
    const int oc = 50 * w + lc;          // this lane's output neuron
    const float w10 = W1[oc * 3 + 0], w11 = W1[oc * 3 + 1], w12 = W1[oc * 3 + 2];
    const float b1j = b1[oc], brj = brec[oc];

    float mem = 0.f;
    unsigned long long bm = 0;           // own word's spike mask

    const float* xp = X + (size_t)b * 3;

    const float* ldsrow  = WT2 + (size_t)lc * 4;
    const int    wbase   = 50 * w;
    float*       spk_out = out_spk + (size_t)b * NHID + wbase + lc;

    // ---- current 8-step group of inputs, fully in registers ----
    float xc[8][3];
#pragma unroll
    for (int k = 0; k < 8; ++k) {
        xc[k][0] = xp[(size_t)k * (BATCH * 3) + 0];
        xc[k][1] = xp[(size_t)k * (BATCH * 3) + 1];
        xc[k][2] = xp[(size_t)k * (BATCH * 3) + 2];
    }

#define REC_WORD(MASK, BASE)                                                          \
    {                                                                                 \
        unsigned long long m = (MASK);                                                \
        while (m) {                                                                   \
            int i0 = __builtin_ctzll(m); m &= m - 1;                                  \
            bool h1 = m != 0; int i1 = h1 ? __builtin_ctzll(m) : i0; if (h1) m &= m - 1; \
            bool h2 = m != 0; int i2 = h2 ? __builtin_ctzll(m) : i0; if (h2) m &= m - 1; \
            bool h3 = m != 0; int i3 = h3 ? __builtin_ctzll(m) : i0; if (h3) m &= m - 1; \
            const float4 v0 = *(const float4*)(ldsrow + (i0 + (BASE)) * ROWF);        \
            const float4 v1 = *(const float4*)(ldsrow + (i1 + (BASE)) * ROWF);        \
            const float4 v2 = *(const float4*)(ldsrow + (i2 + (BASE)) * ROWF);        \
            const float4 v3 = *(const float4*)(ldsrow + (i3 + (BASE)) * ROWF);        \
            pr0 += v0.x; pr1 += v0.y; pr2 += v0.z; pr3 += v0.w;                       \
            if (h1) { pr0 += v1.x; pr1 += v1.y; pr2 += v1.z; pr3 += v1.w; }           \
            if (h2) { pr0 += v2.x; pr1 += v2.y; pr2 += v2.z; pr3 += v2.w; }           \
            if (h3) { pr0 += v3.x; pr1 += v3.y; pr2 += v3.z; pr3 += v3.w; }           \
        }                                                                             \
    }

// One time step (round 13 two-barrier body; x from registers).
#define STEP(T, K)                                                       \
    {                                                                    \
        const int t = (T);                                               \
                                                                         \
        float pr0 = 0.f, pr1 = 0.f, pr2 = 0.f, pr3 = 0.f;                \
        REC_WORD(bm, wbase)                                              \
                                                                         \
        if (l < 50) {                                                    \
            part[0][w][l] = pr0;                                         \
            part[1][w][l] = pr1;                                         \
            part[2][w][l] = pr2;                                         \
            part[3][w][l] = pr3;                                         \
        }                                                                \
        BARRIER_LGKM                                                     \
                                                                         \
        float p0 = part[w][0][lc], p1 = part[w][1][lc];                  \
        float p2 = part[w][2][lc], p3 = part[w][3][lc];                  \
        float rec = ((p0 + p1) + p2) + p3;                               \
        BARRIER_LGKM                                                     \
                                                                         \
        float c1 = fmaf(xc[K][2], w12,                                   \
                        fmaf(xc[K][1], w11, xc[K][0] * w10)) + b1j;      \
        float ba = ((BETA_C * mem + c1) + rec) + brj;                    \
        float nm = (mem > THR_C) ? 0.f : ba;                             \
        float sp = (nm > THR_C) ? 1.f : 0.f;                             \
        mem = nm;                                                        \
                                                                         \
        if (l < 50)                                                      \
            spk_out[(size_t)t * BATCH * NHID] = sp;                      \
        bm = __ballot((l < 50) && (sp > 0.5f));                          \
    }

    for (int g = 0; g < T_STEPS; g += 8) {
        // issue next group's 24 input loads; their SMEM latency is drained
        // once (first barrier of step g), steps g+1..g+7 are SMEM-free
        const int gn = (g + 8 < T_STEPS) ? g + 8 : 0;   // last group: dummy
        float xn[8][3];
#pragma unroll
        for (int k = 0; k < 8; ++k) {
            xn[k][0] = xp[(size_t)(gn + k) * (BATCH * 3) + 0];
            xn[k][1] = xp[(size_t)(gn + k) * (BATCH * 3) + 1];
            xn[k][2] = xp[(size_t)(gn + k) * (BATCH * 3) + 2];
        }

        STEP(g + 0, 0)
        STEP(g + 1, 1)
        STEP(g + 2, 2)
        STEP(g + 3, 3)
        STEP(g + 4, 4)
        STEP(g + 5, 5)
        STEP(g + 6, 6)
        STEP(g + 7, 7)

#pragma unroll
        for (int k = 0; k < 8; ++k) {
            xc[k][0] = xn[k][0];
            xc[k][1] = xn[k][1];
            xc[k][2] = xn[k][2];
        }
    }
#undef STEP
#undef REC_WORD
}

// cur2[t,b] = sum_j spk[t,b,j]*W2[j] + b2 — recomputed from stored spikes
// (L3-resident). Terminal output: tree reduction order is safe.
__launch_bounds__(256)
__global__ void cur2_kernel(const float* __restrict__ spk,
                            const float* __restrict__ W2,
                            const float* __restrict__ b2,
                            float* __restrict__ out) {
    const int lane = threadIdx.x & 63;
    const int wid  = (int)((blockIdx.x * blockDim.x + threadIdx.x) >> 6);
    const int nw   = (int)((gridDim.x * blockDim.x) >> 6);

    float4 w2v = {0.f, 0.f, 0.f, 0.f};
    if (lane < 50) w2v = *(const float4*)(W2 + lane * 4);
    const float b2v = b2[0];

    for (int p = wid; p < T_STEPS * BATCH; p += nw) {
        float4 sv = {0.f, 0.f, 0.f, 0.f};
        if (lane < 50) sv = *(const float4*)(spk + (size_t)p * NHID + lane * 4);
        float a = fmaf(sv.w, w2v.w, fmaf(sv.z, w2v.z,
                  fmaf(sv.y, w2v.y, sv.x * w2v.x)));
#pragma unroll
        for (int o = 32; o >= 1; o >>= 1) a += __shfl_xor(a, o);
        if (lane == 0) out[p] = a + b2v;   // p = t*BATCH + b
    }
}

extern "C" void kernel_launch(void* const* d_in, const int* in_sizes, int n_in,
                              void* d_out, int out_size, void* d_ws, size_t ws_size,
                              hipStream_t stream) {
    const float* X    = (const float*)d_in[0];
    const float* W1   = (const float*)d_in[1];
    const float* b1   = (const float*)d_in[2];
    const float* Wrec = (const float*)d_in[3];
    const float* brec = (const float*)d_in[4];
    const float* W2   = (const float*)d_in[5];
    const float* b2   = (const float*)d_in[6];

    float* out_cur2 = (float*)d_out;                            // [T,B,1] flat
    float* out_spk  = (float*)d_out + (size_t)T_STEPS * BATCH;  // [T,B,200] flat

    rsnn_kernel<<<BATCH, 256, 0, stream>>>(X, W1, b1, Wrec, brec, out_spk);
    cur2_kernel<<<1024, 256, 0, stream>>>(out_spk, W2, b2, out_cur2);
}